// Round 1
// baseline (480.651 us; speedup 1.0000x reference)
//
#include <hip/hip_runtime.h>
#include <math.h>

// Shapes (fixed by the reference): B=1, N=256, H=4, S=256, D=32
#define SEQ 256
#define DH  32
#define CH  32              // key-chunk size staged in LDS
#define NCH (SEQ / CH)

// One block per (n,h) instance; thread tid owns query row s = tid.
// LDS: K chunk [32][32] (4KB) + V chunk [32][32] (4KB) + tri chunk [256][33]
// (33KB, +1 pad -> lane stride 33 = conflict-free) + mask chunk. ~42KB -> 3 blocks/CU.
__global__ __launch_bounds__(256, 3) void TFA_attn_kernel(
    const float* __restrict__ q,
    const float* __restrict__ k,
    const float* __restrict__ v,
    const float* __restrict__ mask_bias,   // [N][SEQ]
    const float* __restrict__ tri_bias,    // [H][SEQ][SEQ]
    float* __restrict__ out)
{
    __shared__ float Kc[CH][DH];
    __shared__ float Vc[CH][DH];
    __shared__ float Tc[SEQ][CH + 1];
    __shared__ float Mc[CH];

    const int tid  = threadIdx.x;
    const int inst = blockIdx.x;          // n*4 + h
    const int n    = inst >> 2;
    const int h    = inst & 3;

    const float scale = 0.17677669529663687f;  // 1/sqrt(32)

    // Load this thread's q row into registers (one-time, 32 floats).
    const float* qrow = q + ((size_t)inst * SEQ + tid) * DH;
    float qr[DH];
    #pragma unroll
    for (int j4 = 0; j4 < DH / 4; ++j4) {
        float4 t = ((const float4*)qrow)[j4];
        qr[j4*4+0] = t.x; qr[j4*4+1] = t.y; qr[j4*4+2] = t.z; qr[j4*4+3] = t.w;
    }

    float acc[DH];
    #pragma unroll
    for (int j = 0; j < DH; ++j) acc[j] = 0.0f;
    float l = 0.0f;

    const float* kbase = k + (size_t)inst * SEQ * DH;
    const float* vbase = v + (size_t)inst * SEQ * DH;
    const float* mbase = mask_bias + (size_t)n * SEQ;
    const float* tbase = tri_bias + (size_t)h * SEQ * SEQ;

    for (int c = 0; c < NCH; ++c) {
        const int t0 = c * CH;
        __syncthreads();   // previous chunk's consumers done before overwrite

        // K,V chunk: CH*DH = 1024 floats = 256 float4; 256 threads -> 1 each,
        // fully coalesced (chunk is contiguous in memory).
        {
            const float4* kg = (const float4*)(kbase + (size_t)t0 * DH);
            const float4* vg = (const float4*)(vbase + (size_t)t0 * DH);
            ((float4*)&Kc[0][0])[tid] = kg[tid];
            ((float4*)&Vc[0][0])[tid] = vg[tid];
        }
        if (tid < CH) Mc[tid] = mbase[t0 + tid];

        // tri chunk: [256 rows][32 cols]; 8 float4 per row, 2048 float4 total
        // -> 8 per thread. Scalar LDS stores (padded row = 132B, not 16B aligned).
        #pragma unroll
        for (int i = 0; i < 8; ++i) {
            int f    = i * 256 + tid;      // float4 index in chunk
            int srow = f >> 3;             // 8 float4 per row
            int j4   = f & 7;
            float4 tv = *(const float4*)(tbase + (size_t)srow * SEQ + t0 + j4 * 4);
            float* dst = &Tc[srow][j4 * 4];
            dst[0] = tv.x; dst[1] = tv.y; dst[2] = tv.z; dst[3] = tv.w;
        }
        __syncthreads();

        const float* trow = &Tc[tid][0];
        #pragma unroll 4
        for (int t = 0; t < CH; ++t) {
            // dot(q_row, K[t]) with 4 partial chains for ILP
            float d0 = 0.f, d1 = 0.f, d2 = 0.f, d3 = 0.f;
            #pragma unroll
            for (int j = 0; j < DH; j += 4) {
                d0 += qr[j+0] * Kc[t][j+0];
                d1 += qr[j+1] * Kc[t][j+1];
                d2 += qr[j+2] * Kc[t][j+2];
                d3 += qr[j+3] * Kc[t][j+3];
            }
            float dot = (d0 + d1) + (d2 + d3);
            float sc  = dot * scale + Mc[t] + trow[t];
            // Scores bounded |sc| < ~12 -> exp without max-subtraction is safe in fp32.
            float p = __expf(sc);
            l += p;
            #pragma unroll
            for (int j = 0; j < DH; ++j) acc[j] += p * Vc[t][j];
        }
    }

    const float inv = 1.0f / l;
    float* orow = out + ((size_t)inst * SEQ + tid) * DH;
    #pragma unroll
    for (int j4 = 0; j4 < DH / 4; ++j4) {
        float4 t;
        t.x = acc[j4*4+0] * inv;
        t.y = acc[j4*4+1] * inv;
        t.z = acc[j4*4+2] * inv;
        t.w = acc[j4*4+3] * inv;
        ((float4*)orow)[j4] = t;
    }
}

extern "C" void kernel_launch(void* const* d_in, const int* in_sizes, int n_in,
                              void* d_out, int out_size, void* d_ws, size_t ws_size,
                              hipStream_t stream) {
    const float* q    = (const float*)d_in[0];
    const float* k    = (const float*)d_in[1];
    const float* v    = (const float*)d_in[2];
    const float* mask = (const float*)d_in[3];
    const float* tri  = (const float*)d_in[4];
    float* out = (float*)d_out;

    const int n_inst = 256 * 4;  // N * H
    TFA_attn_kernel<<<dim3(n_inst), dim3(256), 0, stream>>>(q, k, v, mask, tri, out);
}

// Round 2
// 178.189 us; speedup vs baseline: 2.6974x; 2.6974x over previous
//
#include <hip/hip_runtime.h>

typedef __bf16 bf16;
typedef bf16 bf16x8 __attribute__((ext_vector_type(8)));
typedef bf16 bf16x4 __attribute__((ext_vector_type(4)));
typedef float f32x4 __attribute__((ext_vector_type(4)));

#define SEQ 256
#define DH  32
#define VT_PAD 264   // SEQ+8 -> row stride 528B (16B multiple, bank-spread)
#define P_PAD  40    // row stride 80B (16B multiple; (5*l15+quad)%8 bank spread)

// S^T orientation: S^T = K*Q^T  (M = keys t, N = queries s).
// C-frag lane -> (t = t0 + quad*4 + r, s = s0 + lane&15): tri/mask load as float4,
// P writes pack 4 consecutive t into ds_write_b64.
__global__ __launch_bounds__(256, 4) void attn_mfma_kernel(
    const float* __restrict__ q,
    const float* __restrict__ k,
    const float* __restrict__ v,
    const float* __restrict__ mask_bias,   // [N][SEQ]
    const float* __restrict__ tri_bias,    // [H][SEQ][SEQ]
    float* __restrict__ out)
{
    __shared__ bf16 Vt[DH][VT_PAD];        // V transposed, bf16: 16896 B
    __shared__ bf16 Pb[4][64][P_PAD];      // per-wave P chunk [s:64][t:32]: 20480 B

    const int tid  = threadIdx.x;
    const int wave = tid >> 6;
    const int lane = tid & 63;
    const int l15  = lane & 15;
    const int quad = lane >> 4;

    const int inst = blockIdx.x;           // n*4 + h
    const int n    = inst >> 2;
    const int h    = inst & 3;

    const float* qb = q + (size_t)inst * SEQ * DH;
    const float* kb = k + (size_t)inst * SEQ * DH;
    const float* vb = v + (size_t)inst * SEQ * DH;
    const float* mb = mask_bias + (size_t)n * SEQ;
    const float* tb = tri_bias + (size_t)h * SEQ * SEQ;

    const float K1    = 0.17677669529663687f * 1.44269504088896f; // scale*log2e
    const float LOG2E = 1.44269504088896f;

    // ---- stage V transposed (bf16) into LDS: 2048 float4, 8 per thread ----
    #pragma unroll
    for (int i = 0; i < 8; ++i) {
        int idx = i * 256 + tid;           // float4 index: t = idx>>3, d-group = idx&7
        int t = idx >> 3;
        int d = (idx & 7) * 4;
        float4 tv = ((const float4*)vb)[idx];
        Vt[d + 0][t] = (bf16)tv.x;
        Vt[d + 1][t] = (bf16)tv.y;
        Vt[d + 2][t] = (bf16)tv.z;
        Vt[d + 3][t] = (bf16)tv.w;
    }
    __syncthreads();

    // ---- Q b-frags for this wave's 64 queries (4 s-tiles) ----
    const int s_base = wave * 64;
    bf16x8 qfrag[4];
    #pragma unroll
    for (int st = 0; st < 4; ++st) {
        const float* p = qb + (size_t)(s_base + st * 16 + l15) * DH + quad * 8;
        float4 a = ((const float4*)p)[0];
        float4 b = ((const float4*)p)[1];
        bf16x8 f;
        f[0] = (bf16)a.x; f[1] = (bf16)a.y; f[2] = (bf16)a.z; f[3] = (bf16)a.w;
        f[4] = (bf16)b.x; f[5] = (bf16)b.y; f[6] = (bf16)b.z; f[7] = (bf16)b.w;
        qfrag[st] = f;
    }

    f32x4 oacc[4][2];
    #pragma unroll
    for (int st = 0; st < 4; ++st)
        #pragma unroll
        for (int dt = 0; dt < 2; ++dt)
            oacc[st][dt] = (f32x4){0.f, 0.f, 0.f, 0.f};
    float lpart[4] = {0.f, 0.f, 0.f, 0.f};

    const f32x4 zero4 = {0.f, 0.f, 0.f, 0.f};

    // ---- main loop: 8 chunks of 32 keys ----
    for (int c = 0; c < 8; ++c) {
        #pragma unroll
        for (int half = 0; half < 2; ++half) {
            const int mt = c * 2 + half;
            const int t0 = mt * 16;

            // K a-frag: K[t0+l15][quad*8 .. +7] (contiguous 32B)
            const float* kp = kb + (size_t)(t0 + l15) * DH + quad * 8;
            float4 ka = ((const float4*)kp)[0];
            float4 kc = ((const float4*)kp)[1];
            bf16x8 kfrag;
            kfrag[0] = (bf16)ka.x; kfrag[1] = (bf16)ka.y;
            kfrag[2] = (bf16)ka.z; kfrag[3] = (bf16)ka.w;
            kfrag[4] = (bf16)kc.x; kfrag[5] = (bf16)kc.y;
            kfrag[6] = (bf16)kc.z; kfrag[7] = (bf16)kc.w;

            // biases for t = t0 + quad*4 + r (float4, consecutive t)
            float4 mk = *(const float4*)(mb + t0 + quad * 4);
            float4 tr[4];
            #pragma unroll
            for (int st = 0; st < 4; ++st) {
                const float* tp = tb + (size_t)(s_base + st * 16 + l15) * SEQ + t0 + quad * 4;
                tr[st] = *(const float4*)tp;
            }
            float mkl0 = mk.x * LOG2E, mkl1 = mk.y * LOG2E;
            float mkl2 = mk.z * LOG2E, mkl3 = mk.w * LOG2E;

            // S^T tiles: 4 independent MFMAs
            f32x4 cf[4];
            #pragma unroll
            for (int st = 0; st < 4; ++st)
                cf[st] = __builtin_amdgcn_mfma_f32_16x16x32_bf16(kfrag, qfrag[st], zero4, 0, 0, 0);

            // p = exp2(c*K1 + (mask+tri)*log2e); accumulate row sums; pack to LDS
            #pragma unroll
            for (int st = 0; st < 4; ++st) {
                float p0 = __builtin_amdgcn_exp2f(fmaf(tr[st].x, LOG2E, fmaf(cf[st][0], K1, mkl0)));
                float p1 = __builtin_amdgcn_exp2f(fmaf(tr[st].y, LOG2E, fmaf(cf[st][1], K1, mkl1)));
                float p2 = __builtin_amdgcn_exp2f(fmaf(tr[st].z, LOG2E, fmaf(cf[st][2], K1, mkl2)));
                float p3 = __builtin_amdgcn_exp2f(fmaf(tr[st].w, LOG2E, fmaf(cf[st][3], K1, mkl3)));
                lpart[st] += (p0 + p1) + (p2 + p3);
                bf16x4 pk;
                pk[0] = (bf16)p0; pk[1] = (bf16)p1; pk[2] = (bf16)p2; pk[3] = (bf16)p3;
                *(bf16x4*)&Pb[wave][st * 16 + l15][half * 16 + quad * 4] = pk;
            }
        }

        // ---- PV k-step over this 32-key chunk ----
        bf16x8 vf[2];
        #pragma unroll
        for (int dt = 0; dt < 2; ++dt)
            vf[dt] = *(const bf16x8*)&Vt[dt * 16 + l15][c * 32 + quad * 8];
        #pragma unroll
        for (int st = 0; st < 4; ++st) {
            bf16x8 pf = *(const bf16x8*)&Pb[wave][st * 16 + l15][quad * 8];
            #pragma unroll
            for (int dt = 0; dt < 2; ++dt)
                oacc[st][dt] = __builtin_amdgcn_mfma_f32_16x16x32_bf16(pf, vf[dt], oacc[st][dt], 0, 0, 0);
        }
    }

    // ---- softmax denominators: reduce across quads, then normalize+store ----
    float linv[4];
    #pragma unroll
    for (int st = 0; st < 4; ++st) {
        float x = lpart[st];
        x += __shfl_xor(x, 16);
        x += __shfl_xor(x, 32);
        linv[st] = 1.0f / x;   // valid for s = s_base + st*16 + l15, all quads hold it
    }

    float* ob = out + (size_t)inst * SEQ * DH;
    #pragma unroll
    for (int st = 0; st < 4; ++st) {
        #pragma unroll
        for (int r = 0; r < 4; ++r) {
            // need 1/l at s-row = st*16 + quad*4 + r -> lives in lane (quad*4+r)
            float invr = __shfl(linv[st], quad * 4 + r);
            int s = s_base + st * 16 + quad * 4 + r;
            float* orow = ob + (size_t)s * DH;
            orow[l15]      = oacc[st][0][r] * invr;
            orow[16 + l15] = oacc[st][1][r] * invr;
        }
    }
}

extern "C" void kernel_launch(void* const* d_in, const int* in_sizes, int n_in,
                              void* d_out, int out_size, void* d_ws, size_t ws_size,
                              hipStream_t stream) {
    const float* q    = (const float*)d_in[0];
    const float* k    = (const float*)d_in[1];
    const float* v    = (const float*)d_in[2];
    const float* mask = (const float*)d_in[3];
    const float* tri  = (const float*)d_in[4];
    float* out = (float*)d_out;

    attn_mfma_kernel<<<dim3(256 * 4), dim3(256), 0, stream>>>(q, k, v, mask, tri, out);
}